// Round 7
// baseline (606.801 us; speedup 1.0000x reference)
//
#include <hip/hip_runtime.h>
#include <hip/hip_bf16.h>
#include <stdint.h>

#define N_DIM 8192
#define D_DIM 512
#define BM 128
#define BN 128
#define BK 64
#define RSTR 140   // recs row stride in bf16 elems
#define TPB 4      // tiles chained per block (same tile_m row)

typedef __attribute__((ext_vector_type(8))) short bf16x8;
typedef __attribute__((ext_vector_type(4))) float f32x4;
typedef __attribute__((ext_vector_type(4))) unsigned int u32x4;

__device__ __forceinline__ unsigned short f2bf(float f) {
    unsigned int x = __float_as_uint(f);
    x += 0x7fffu + ((x >> 16) & 1u);
    return (unsigned short)(x >> 16);
}
__device__ __forceinline__ float bf2f(unsigned short u) {
    return __uint_as_float(((unsigned int)u) << 16);
}

// ---------------- prep: f32 -> bf16, plus row squared norms ----------------
__global__ void __launch_bounds__(256) prep_kernel(
    const float* __restrict__ U, const float* __restrict__ V,
    unsigned short* __restrict__ Ub, unsigned short* __restrict__ Vb,
    float* __restrict__ usq, float* __restrict__ vsq)
{
    int row = blockIdx.x;
    const float* src;
    unsigned short* dst;
    float* sq;
    if (row < N_DIM) {
        src = U + (size_t)row * D_DIM;
        dst = Ub + (size_t)row * D_DIM;
        sq  = usq + row;
    } else {
        int r = row - N_DIM;
        src = V + (size_t)r * D_DIM;
        dst = Vb + (size_t)r * D_DIM;
        sq  = vsq + r;
    }
    int t = threadIdx.x;
    float2 v = *reinterpret_cast<const float2*>(src + 2 * t);
    float s = v.x * v.x + v.y * v.y;
    ushort2 b;
    b.x = f2bf(v.x);
    b.y = f2bf(v.y);
    *reinterpret_cast<ushort2*>(dst + 2 * t) = b;

    #pragma unroll
    for (int o = 32; o > 0; o >>= 1) s += __shfl_down(s, o, 64);
    __shared__ float red[4];
    if ((t & 63) == 0) red[t >> 6] = s;
    __syncthreads();
    if (t == 0) *sq = red[0] + red[1] + red[2] + red[3];
}

// ---------------- fused GEMM + loss, producer/consumer wave-specialized ----------------
// 512 threads: waves 0-3 = GEMM (reg-stage -> ds_write -> lgkm-only barrier -> MFMA),
// waves 4-7 = M/W streamers with a dedicated vmcnt queue: depth-3 lookahead over
// 4 named register sets, loads stay in flight ACROSS raw s_barriers (no vmcnt drain).
// Rec handoff per tile via bf16 LDS buffer. Barrier count identical in both roles.
__global__ void __launch_bounds__(512, 4) fused_kernel(
    const unsigned short* __restrict__ Ub, const unsigned short* __restrict__ Vb,
    const float* __restrict__ Mg, const float* __restrict__ Wg,
    const float* __restrict__ usq, const float* __restrict__ vsq,
    double* __restrict__ acc)
{
    __shared__ alignas(16) char smem[BM * BK * 2 + BN * BK * 2];   // 32 KiB staging
    __shared__ alignas(16) unsigned short recs[BM * RSTR];          // 35 KiB bf16 rec
    __shared__ float red1[8], red2[8];
    char* As = smem;
    char* Bs = smem + BM * BK * 2;

    const int t    = threadIdx.x;
    const int lane = t & 63;
    const int wave = t >> 6;
    const bool gw  = (wave < 4);     // GEMM waves
    const int wm   = wave >> 1;      // valid for gw
    const int wn   = wave & 1;

    const int bid    = blockIdx.x;   // 0..1023
    const int tile_m = bid >> 4;
    const int quad   = bid & 15;
    const int row0   = tile_m * BM;

    // streaming-thread coords (waves 4-7)
    const int ts = t - 256;          // 0..255 for streamers
    const int rg = ts >> 4;          // 0..15 row within 16-row chunk
    const int c8 = (ts & 15) * 8;    // 0..120 col slice

    float s1 = 0.f, s2 = 0.f;

    // ---- streaming state: 4 named sets (all indices compile-time after unroll) ----
    int   colp = 0;
    f32x4 vs0, vs1;
    f32x4 ms0[4], ms1[4], ws0[4], ws1[4];
    float uss[4];

    auto issue = [&](int chunk, int set) {
        int r = chunk * 16 + rg;
        const float* Mp = Mg + (size_t)(row0 + r) * N_DIM + colp + c8;
        const float* Wp = Wg + (size_t)(row0 + r) * N_DIM + colp + c8;
        ms0[set] = *reinterpret_cast<const f32x4*>(Mp);
        ms1[set] = *reinterpret_cast<const f32x4*>(Mp + 4);
        ws0[set] = *reinterpret_cast<const f32x4*>(Wp);
        ws1[set] = *reinterpret_cast<const f32x4*>(Wp + 4);
        uss[set] = usq[row0 + r];
    };
    auto consume = [&](int chunk, int set) {
        int r = chunk * 16 + rg;
        bf16x8 rb = *reinterpret_cast<const bf16x8*>(&recs[r * RSTR + c8]);
        #pragma unroll
        for (int c = 0; c < 4; ++c) {
            float rc = bf2f((unsigned short)rb[c]);
            float d  = rc - ms0[set][c];
            s1 = fmaf(d, d, s1);
            s2 = fmaf(ws0[set][c], uss[set] + vs0[c] - 2.f * rc, s2);
        }
        #pragma unroll
        for (int c = 0; c < 4; ++c) {
            float rc = bf2f((unsigned short)rb[4 + c]);
            float d  = rc - ms1[set][c];
            s1 = fmaf(d, d, s1);
            s2 = fmaf(ws1[set][c], uss[set] + vs1[c] - 2.f * rc, s2);
        }
    };

    // ---- GEMM staging: global->reg (vmcnt), ds_write swizzled (lgkm) ----
    auto stage_load = [&](const unsigned short* Ua, const unsigned short* Va, int k0,
                          u32x4 (&sa)[4], u32x4 (&sb)[4]) {
        #pragma unroll
        for (int c = 0; c < 4; ++c) {
            int s   = c * 256 + t;   // t in [0,256) for gw
            int row = s >> 3;
            int kg  = s & 7;
            sa[c] = *reinterpret_cast<const u32x4*>(Ua + (size_t)row * D_DIM + k0 + kg * 8);
            sb[c] = *reinterpret_cast<const u32x4*>(Va + (size_t)row * D_DIM + k0 + kg * 8);
        }
    };
    auto stage_write = [&](u32x4 (&sa)[4], u32x4 (&sb)[4]) {
        #pragma unroll
        for (int c = 0; c < 4; ++c) {
            int s   = c * 256 + t;
            int row = s >> 3;
            int kg  = s & 7;
            int kgs = kg ^ (row & 7);
            *reinterpret_cast<u32x4*>(As + row * (BK * 2) + kgs * 16) = sa[c];
            *reinterpret_cast<u32x4*>(Bs + row * (BK * 2) + kgs * 16) = sb[c];
        }
    };

    auto mma = [&](f32x4 (&a)[4][4]) {
        #pragma unroll
        for (int kc = 0; kc < 2; ++kc) {
            bf16x8 af[4], bfr[4];
            const int kgw = kc * 4 + (lane >> 4);
            #pragma unroll
            for (int i = 0; i < 4; ++i) {
                int ra = wm * 64 + i * 16 + (lane & 15);
                af[i]  = *reinterpret_cast<const bf16x8*>(As + ra * (BK * 2) + ((kgw ^ (ra & 7)) * 16));
                int rb = wn * 64 + i * 16 + (lane & 15);
                bfr[i] = *reinterpret_cast<const bf16x8*>(Bs + rb * (BK * 2) + ((kgw ^ (rb & 7)) * 16));
            }
            #pragma unroll
            for (int i = 0; i < 4; ++i)
                #pragma unroll
                for (int j = 0; j < 4; ++j)
                    a[i][j] = __builtin_amdgcn_mfma_f32_16x16x32_bf16(af[i], bfr[j], a[i][j], 0, 0, 0);
        }
    };

    // C/D layout (16x16x32): col = lane&15, row = (lane>>4)*4 + reg
    auto dump = [&](f32x4 (&a)[4][4]) {
        #pragma unroll
        for (int i = 0; i < 4; ++i)
            #pragma unroll
            for (int j = 0; j < 4; ++j)
                #pragma unroll
                for (int q = 0; q < 4; ++q) {
                    int r = wm * 64 + i * 16 + (lane >> 4) * 4 + q;
                    int c = wn * 64 + j * 16 + (lane & 15);
                    recs[r * RSTR + c] = f2bf(a[i][j][q]);
                }
    };

    #define LGKM0_BAR() do { \
        asm volatile("s_waitcnt lgkmcnt(0)" ::: "memory"); \
        __builtin_amdgcn_s_barrier(); } while (0)

    const f32x4 zero = {0.f, 0.f, 0.f, 0.f};
    const unsigned short* Ua = Ub + (size_t)row0 * D_DIM;
    f32x4 a[4][4];
    u32x4 sa[4], sb[4];

    for (int it = 0; it < TPB; ++it) {
        const int col0 = (quad * TPB + it) * BN;
        const unsigned short* Va = Vb + (size_t)col0 * D_DIM;
        const bool strm = (it > 0);

        if (gw) {
            #pragma unroll
            for (int i = 0; i < 4; ++i)
                #pragma unroll
                for (int j = 0; j < 4; ++j) a[i][j] = zero;
        } else if (strm) {
            colp = col0 - BN;
            vs0 = *reinterpret_cast<const f32x4*>(vsq + colp + c8);
            vs1 = *reinterpret_cast<const f32x4*>(vsq + colp + c8 + 4);
        }

        #pragma unroll
        for (int kt = 0; kt < 8; ++kt) {
            if (gw) {
                stage_load(Ua, Va, kt * BK, sa, sb);
                stage_write(sa, sb);
            } else if (strm) {
                issue(kt, kt & 3);
            }
            LGKM0_BAR();                 // stage visible; no vmcnt drain
            if (gw) {
                mma(a);
            } else if (strm && kt >= 3) {
                consume(kt - 3, (kt - 3) & 3);
            }
            LGKM0_BAR();                 // LDS reusable next step
        }
        if (!gw && strm) {               // drain chunks 5,6,7 of previous tile
            consume(5, 1);
            consume(6, 2);
            consume(7, 3);
        }
        LGKM0_BAR();                     // BAR3: recs free for overwrite
        if (gw) dump(a);                 // visible at next LGKM0_BAR
    }

    // ---- final tile's streaming (exposed, deep-pipelined by streamers only) ----
    LGKM0_BAR();                         // dump of last tile visible
    if (!gw) {
        colp = (quad * TPB + TPB - 1) * BN;
        vs0 = *reinterpret_cast<const f32x4*>(vsq + colp + c8);
        vs1 = *reinterpret_cast<const f32x4*>(vsq + colp + c8 + 4);
        issue(0, 0); issue(1, 1); issue(2, 2);
        consume(0, 0); issue(3, 3);
        consume(1, 1); issue(4, 0);
        consume(2, 2); issue(5, 1);
        consume(3, 3); issue(6, 2);
        consume(4, 0); issue(7, 3);
        consume(5, 1);
        consume(6, 2);
        consume(7, 3);
    }

    // ---- block reduction + atomics ----
    #pragma unroll
    for (int o = 32; o > 0; o >>= 1) {
        s1 += __shfl_down(s1, o, 64);
        s2 += __shfl_down(s2, o, 64);
    }
    if (lane == 0) { red1[wave] = s1; red2[wave] = s2; }
    __syncthreads();
    if (t == 0) {
        double a1s = 0.0, a2s = 0.0;
        #pragma unroll
        for (int wv = 0; wv < 8; ++wv) { a1s += red1[wv]; a2s += red2[wv]; }
        atomicAdd(acc, a1s);
        atomicAdd(acc + 1, a2s);
    }
    #undef LGKM0_BAR
}

// ---------------- finalize ----------------
__global__ void finalize_kernel(const double* __restrict__ acc,
                                const float* __restrict__ alpha,
                                float* __restrict__ out)
{
    double tot = acc[0] + (double)alpha[0] * acc[1];
    out[0] = (float)(tot / ((double)N_DIM * (double)N_DIM));
}

extern "C" void kernel_launch(void* const* d_in, const int* in_sizes, int n_in,
                              void* d_out, int out_size, void* d_ws, size_t ws_size,
                              hipStream_t stream) {
    const float* U     = (const float*)d_in[0];
    const float* V     = (const float*)d_in[1];
    const float* Mg    = (const float*)d_in[2];
    const float* Wg    = (const float*)d_in[3];
    const float* alpha = (const float*)d_in[4];

    char* ws = (char*)d_ws;
    unsigned short* Ub = (unsigned short*)ws;                          // 8 MiB
    unsigned short* Vb = (unsigned short*)(ws + 8u * 1024 * 1024);     // 8 MiB
    float* usq = (float*)(ws + 16u * 1024 * 1024);                     // 32 KiB
    float* vsq = (float*)(ws + 16u * 1024 * 1024 + 32u * 1024);       // 32 KiB
    double* acc = (double*)(ws + 16u * 1024 * 1024 + 64u * 1024);     // 16 B

    hipMemsetAsync(acc, 0, 2 * sizeof(double), stream);
    prep_kernel<<<2 * N_DIM, 256, 0, stream>>>(U, V, Ub, Vb, usq, vsq);
    fused_kernel<<<(N_DIM / BM) * (N_DIM / BN) / TPB, 512, 0, stream>>>(
        Ub, Vb, Mg, Wg, usq, vsq, acc);
    finalize_kernel<<<1, 1, 0, stream>>>(acc, alpha, (float*)d_out);
}

// Round 8
// 339.214 us; speedup vs baseline: 1.7888x; 1.7888x over previous
//
#include <hip/hip_runtime.h>
#include <hip/hip_bf16.h>
#include <stdint.h>

#define N_DIM 8192
#define D_DIM 512
#define BM 128
#define BN 128
#define BK 64
#define RSTR 140   // recs row stride in bf16 elems
#define TPB 4      // tiles chained per block (same tile_m row)

typedef __attribute__((ext_vector_type(8))) short bf16x8;
typedef __attribute__((ext_vector_type(4))) float f32x4;
typedef __attribute__((ext_vector_type(4))) unsigned int u32x4;

__device__ __forceinline__ unsigned short f2bf(float f) {
    unsigned int x = __float_as_uint(f);
    x += 0x7fffu + ((x >> 16) & 1u);
    return (unsigned short)(x >> 16);
}
__device__ __forceinline__ float bf2f(unsigned short u) {
    return __uint_as_float(((unsigned int)u) << 16);
}

// ---------------- prep: f32 -> bf16, plus row squared norms ----------------
__global__ void __launch_bounds__(256) prep_kernel(
    const float* __restrict__ U, const float* __restrict__ V,
    unsigned short* __restrict__ Ub, unsigned short* __restrict__ Vb,
    float* __restrict__ usq, float* __restrict__ vsq)
{
    int row = blockIdx.x;
    const float* src;
    unsigned short* dst;
    float* sq;
    if (row < N_DIM) {
        src = U + (size_t)row * D_DIM;
        dst = Ub + (size_t)row * D_DIM;
        sq  = usq + row;
    } else {
        int r = row - N_DIM;
        src = V + (size_t)r * D_DIM;
        dst = Vb + (size_t)r * D_DIM;
        sq  = vsq + r;
    }
    int t = threadIdx.x;
    float2 v = *reinterpret_cast<const float2*>(src + 2 * t);
    float s = v.x * v.x + v.y * v.y;
    ushort2 b;
    b.x = f2bf(v.x);
    b.y = f2bf(v.y);
    *reinterpret_cast<ushort2*>(dst + 2 * t) = b;

    #pragma unroll
    for (int o = 32; o > 0; o >>= 1) s += __shfl_down(s, o, 64);
    __shared__ float red[4];
    if ((t & 63) == 0) red[t >> 6] = s;
    __syncthreads();
    if (t == 0) *sq = red[0] + red[1] + red[2] + red[3];
}

// ---------------- fused GEMM + loss, tile-chained, deep-pipelined ----------------
// Per K-step: reg-dbuf staging (stage_load(kt+1) issued at top; ds_write of kt
// follows -> global latency leaves the critical path) + M/W streamed for the
// PREVIOUS tile with 3-K-step lookahead over 4 rotating register sets.
// Raw s_barrier + lgkmcnt(0) only -- vmcnt is never drained, so M/W loads fly
// ~2 K-steps (>= HBM latency). Rec handoff via bf16 LDS buffer.
__global__ void __launch_bounds__(256, 2) fused_kernel(
    const unsigned short* __restrict__ Ub, const unsigned short* __restrict__ Vb,
    const float* __restrict__ Mg, const float* __restrict__ Wg,
    const float* __restrict__ usq, const float* __restrict__ vsq,
    double* __restrict__ acc)
{
    __shared__ alignas(16) char smem[BM * BK * 2 + BN * BK * 2];   // 32 KiB staging
    __shared__ alignas(16) unsigned short recs[BM * RSTR];          // 35 KiB bf16 rec
    __shared__ float red1[4], red2[4];
    char* As = smem;
    char* Bs = smem + BM * BK * 2;

    const int t    = threadIdx.x;
    const int lane = t & 63;
    const int wave = t >> 6;
    const int wm   = wave >> 1;
    const int wn   = wave & 1;

    const int bid    = blockIdx.x;   // 0..1023
    const int tile_m = bid >> 4;
    const int quad   = bid & 15;
    const int row0   = tile_m * BM;

    const int rg = t >> 4;           // 0..15: row within 16-row chunk
    const int c8 = (t & 15) * 8;     // 0..120: 8-float column slice

    float s1 = 0.f, s2 = 0.f;

    // ---- M/W streaming state: 4 rotating sets (const-indexed after unroll) ----
    int   colp = 0;
    f32x4 vs0, vs1;
    f32x4 ms0[4], ms1[4], ws0[4], ws1[4];
    float uss[4];

    auto issue = [&](int chunk, int set) {
        int r = chunk * 16 + rg;
        const float* Mp = Mg + (size_t)(row0 + r) * N_DIM + colp + c8;
        const float* Wp = Wg + (size_t)(row0 + r) * N_DIM + colp + c8;
        ms0[set] = *reinterpret_cast<const f32x4*>(Mp);
        ms1[set] = *reinterpret_cast<const f32x4*>(Mp + 4);
        ws0[set] = *reinterpret_cast<const f32x4*>(Wp);
        ws1[set] = *reinterpret_cast<const f32x4*>(Wp + 4);
        uss[set] = usq[row0 + r];
    };
    auto consume = [&](int chunk, int set) {
        int r = chunk * 16 + rg;
        bf16x8 rb = *reinterpret_cast<const bf16x8*>(&recs[r * RSTR + c8]);
        #pragma unroll
        for (int c = 0; c < 4; ++c) {
            float rc = bf2f((unsigned short)rb[c]);
            float d  = rc - ms0[set][c];
            s1 = fmaf(d, d, s1);
            s2 = fmaf(ws0[set][c], uss[set] + vs0[c] - 2.f * rc, s2);
        }
        #pragma unroll
        for (int c = 0; c < 4; ++c) {
            float rc = bf2f((unsigned short)rb[4 + c]);
            float d  = rc - ms1[set][c];
            s1 = fmaf(d, d, s1);
            s2 = fmaf(ws1[set][c], uss[set] + vs1[c] - 2.f * rc, s2);
        }
    };

    // ---- staging: global->reg (vmcnt), ds_write swizzled (lgkm) ----
    auto stage_load = [&](const unsigned short* Va, int k0,
                          u32x4 (&sa)[4], u32x4 (&sb)[4]) {
        const unsigned short* Ua = Ub + (size_t)row0 * D_DIM;
        #pragma unroll
        for (int c = 0; c < 4; ++c) {
            int s   = c * 256 + t;
            int row = s >> 3;
            int kg  = s & 7;
            sa[c] = *reinterpret_cast<const u32x4*>(Ua + (size_t)row * D_DIM + k0 + kg * 8);
            sb[c] = *reinterpret_cast<const u32x4*>(Va + (size_t)row * D_DIM + k0 + kg * 8);
        }
    };
    auto stage_write = [&](u32x4 (&sa)[4], u32x4 (&sb)[4]) {
        #pragma unroll
        for (int c = 0; c < 4; ++c) {
            int s   = c * 256 + t;
            int row = s >> 3;
            int kg  = s & 7;
            int kgs = kg ^ (row & 7);
            *reinterpret_cast<u32x4*>(As + row * (BK * 2) + kgs * 16) = sa[c];
            *reinterpret_cast<u32x4*>(Bs + row * (BK * 2) + kgs * 16) = sb[c];
        }
    };

    auto mma = [&](f32x4 (&a)[4][4]) {
        #pragma unroll
        for (int kc = 0; kc < 2; ++kc) {
            bf16x8 af[4], bfr[4];
            const int kgw = kc * 4 + (lane >> 4);
            #pragma unroll
            for (int i = 0; i < 4; ++i) {
                int ra = wm * 64 + i * 16 + (lane & 15);
                af[i]  = *reinterpret_cast<const bf16x8*>(As + ra * (BK * 2) + ((kgw ^ (ra & 7)) * 16));
                int rb = wn * 64 + i * 16 + (lane & 15);
                bfr[i] = *reinterpret_cast<const bf16x8*>(Bs + rb * (BK * 2) + ((kgw ^ (rb & 7)) * 16));
            }
            #pragma unroll
            for (int i = 0; i < 4; ++i)
                #pragma unroll
                for (int j = 0; j < 4; ++j)
                    a[i][j] = __builtin_amdgcn_mfma_f32_16x16x32_bf16(af[i], bfr[j], a[i][j], 0, 0, 0);
        }
    };

    // C/D layout (16x16x32): col = lane&15, row = (lane>>4)*4 + reg
    auto dump = [&](f32x4 (&a)[4][4]) {
        #pragma unroll
        for (int i = 0; i < 4; ++i)
            #pragma unroll
            for (int j = 0; j < 4; ++j)
                #pragma unroll
                for (int q = 0; q < 4; ++q) {
                    int r = wm * 64 + i * 16 + (lane >> 4) * 4 + q;
                    int c = wn * 64 + j * 16 + (lane & 15);
                    recs[r * RSTR + c] = f2bf(a[i][j][q]);
                }
    };

    #define FENCE() asm volatile("" ::: "memory")
    #define LGKM0_BAR() do { \
        asm volatile("s_waitcnt lgkmcnt(0)" ::: "memory"); \
        __builtin_amdgcn_s_barrier(); } while (0)

    const f32x4 zero = {0.f, 0.f, 0.f, 0.f};
    f32x4 a[4][4];
    u32x4 sa0[4], sb0[4], sa1[4], sb1[4];   // two staging register sets

    // prologue: stage k=0 of tile 0
    stage_load(Vb + (size_t)(quad * TPB) * BN * D_DIM, 0, sa0, sb0);

    for (int it = 0; it < TPB; ++it) {
        const int col0 = (quad * TPB + it) * BN;
        const unsigned short* Va  = Vb + (size_t)col0 * D_DIM;
        const unsigned short* Van = Vb + (size_t)(col0 + BN) * D_DIM;  // next tile (unused for it=3)
        const bool strm = (it > 0);

        #pragma unroll
        for (int i = 0; i < 4; ++i)
            #pragma unroll
            for (int j = 0; j < 4; ++j) a[i][j] = zero;

        if (strm) {
            colp = col0 - BN;
            vs0 = *reinterpret_cast<const f32x4*>(vsq + colp + c8);
            vs1 = *reinterpret_cast<const f32x4*>(vsq + colp + c8 + 4);
            issue(0, 0);
            issue(1, 1);
            issue(2, 2);
        }

        #pragma unroll
        for (int kt = 0; kt < 8; ++kt) {
            // cur = set loaded last iter; nxt = set to prefetch into
            if ((kt & 1) == 0) {
                if (kt < 7)           stage_load(Va, (kt + 1) * BK, sa1, sb1);
                else if (it < TPB-1)  stage_load(Van, 0, sa1, sb1);
            } else {
                if (kt < 7)           stage_load(Va, (kt + 1) * BK, sa0, sb0);
                else if (it < TPB-1)  stage_load(Van, 0, sa0, sb0);
            }
            FENCE();
            if (strm && kt < 5) issue(kt + 3, (kt + 3) & 3);
            FENCE();
            if ((kt & 1) == 0) stage_write(sa0, sb0);
            else               stage_write(sa1, sb1);
            LGKM0_BAR();                 // staging visible; vmcnt NOT drained
            mma(a);
            if (strm) consume(kt, kt & 3);
            LGKM0_BAR();                 // LDS (staging + recs) reusable
        }
        dump(a);                         // all recs reads finished before last barrier
        LGKM0_BAR();                     // dump visible for next tile's consumes
    }

    // ---- exposed streaming for the last tile's rec ----
    colp = (quad * TPB + TPB - 1) * BN;
    vs0 = *reinterpret_cast<const f32x4*>(vsq + colp + c8);
    vs1 = *reinterpret_cast<const f32x4*>(vsq + colp + c8 + 4);
    issue(0, 0); issue(1, 1); issue(2, 2);
    consume(0, 0); issue(3, 3);
    consume(1, 1); issue(4, 0);
    consume(2, 2); issue(5, 1);
    consume(3, 3); issue(6, 2);
    consume(4, 0); issue(7, 3);
    consume(5, 1);
    consume(6, 2);
    consume(7, 3);

    // ---- block reduction + atomics ----
    #pragma unroll
    for (int o = 32; o > 0; o >>= 1) {
        s1 += __shfl_down(s1, o, 64);
        s2 += __shfl_down(s2, o, 64);
    }
    if (lane == 0) { red1[wave] = s1; red2[wave] = s2; }
    __syncthreads();
    if (t == 0) {
        double a1s = (double)red1[0] + red1[1] + red1[2] + red1[3];
        double a2s = (double)red2[0] + red2[1] + red2[2] + red2[3];
        atomicAdd(acc, a1s);
        atomicAdd(acc + 1, a2s);
    }
    #undef FENCE
    #undef LGKM0_BAR
}

// ---------------- finalize ----------------
__global__ void finalize_kernel(const double* __restrict__ acc,
                                const float* __restrict__ alpha,
                                float* __restrict__ out)
{
    double tot = acc[0] + (double)alpha[0] * acc[1];
    out[0] = (float)(tot / ((double)N_DIM * (double)N_DIM));
}

extern "C" void kernel_launch(void* const* d_in, const int* in_sizes, int n_in,
                              void* d_out, int out_size, void* d_ws, size_t ws_size,
                              hipStream_t stream) {
    const float* U     = (const float*)d_in[0];
    const float* V     = (const float*)d_in[1];
    const float* Mg    = (const float*)d_in[2];
    const float* Wg    = (const float*)d_in[3];
    const float* alpha = (const float*)d_in[4];

    char* ws = (char*)d_ws;
    unsigned short* Ub = (unsigned short*)ws;                          // 8 MiB
    unsigned short* Vb = (unsigned short*)(ws + 8u * 1024 * 1024);     // 8 MiB
    float* usq = (float*)(ws + 16u * 1024 * 1024);                     // 32 KiB
    float* vsq = (float*)(ws + 16u * 1024 * 1024 + 32u * 1024);       // 32 KiB
    double* acc = (double*)(ws + 16u * 1024 * 1024 + 64u * 1024);     // 16 B

    hipMemsetAsync(acc, 0, 2 * sizeof(double), stream);
    prep_kernel<<<2 * N_DIM, 256, 0, stream>>>(U, V, Ub, Vb, usq, vsq);
    fused_kernel<<<(N_DIM / BM) * (N_DIM / BN) / TPB, 256, 0, stream>>>(
        Ub, Vb, Mg, Wg, usq, vsq, acc);
    finalize_kernel<<<1, 1, 0, stream>>>(acc, alpha, (float*)d_out);
}

// Round 9
// 292.932 us; speedup vs baseline: 2.0715x; 1.1580x over previous
//
#include <hip/hip_runtime.h>
#include <hip/hip_bf16.h>
#include <stdint.h>

#define N_DIM 8192
#define D_DIM 512
#define BM 128
#define BN 128
#define BK 64

typedef __attribute__((ext_vector_type(8))) short bf16x8;
typedef __attribute__((ext_vector_type(4))) float f32x4;

__device__ __forceinline__ unsigned short f2bf(float f) {
    unsigned int x = __float_as_uint(f);
    x += 0x7fffu + ((x >> 16) & 1u);
    return (unsigned short)(x >> 16);
}

// ---------------- prep: f32 -> bf16, plus row squared norms ----------------
__global__ void __launch_bounds__(256) prep_kernel(
    const float* __restrict__ U, const float* __restrict__ V,
    unsigned short* __restrict__ Ub, unsigned short* __restrict__ Vb,
    float* __restrict__ usq, float* __restrict__ vsq)
{
    int row = blockIdx.x;
    const float* src;
    unsigned short* dst;
    float* sq;
    if (row < N_DIM) {
        src = U + (size_t)row * D_DIM;
        dst = Ub + (size_t)row * D_DIM;
        sq  = usq + row;
    } else {
        int r = row - N_DIM;
        src = V + (size_t)r * D_DIM;
        dst = Vb + (size_t)r * D_DIM;
        sq  = vsq + r;
    }
    int t = threadIdx.x;
    float2 v = *reinterpret_cast<const float2*>(src + 2 * t);
    float s = v.x * v.x + v.y * v.y;
    ushort2 b;
    b.x = f2bf(v.x);
    b.y = f2bf(v.y);
    *reinterpret_cast<ushort2*>(dst + 2 * t) = b;

    #pragma unroll
    for (int o = 32; o > 0; o >>= 1) s += __shfl_down(s, o, 64);
    __shared__ float red[4];
    if ((t & 63) == 0) red[t >> 6] = s;
    __syncthreads();
    if (t == 0) *sq = red[0] + red[1] + red[2] + red[3];
}

// ---------------- fused GEMM + loss-reduction kernel ----------------
// R1 structure + R2 epilogue, fixed:
//  - GEMM: global_load_lds staging (linear LDS dest, inverse-swizzled global
//    source), XOR-swizzled ds_read_b128, mfma 16x16x32; acc lives in AGPRs.
//  - Epilogue: acc -> recs (reused 32 KB staging LDS, two 64-row halves of
//    64x128 f32, columns XOR-swizzled cg^=(r&7): conflict-free writes+reads).
//    M/W streamed as f32x4 via 3 named register sets pipelined ACROSS raw
//    s_barrier + lgkmcnt(0) barriers -- vmcnt never drained in the epilogue.
//  - Row-major block mapping (R1's) for replay-to-replay L3 retention.
__global__ void __launch_bounds__(256, 3) fused_kernel(
    const unsigned short* __restrict__ Ub, const unsigned short* __restrict__ Vb,
    const float* __restrict__ Mg, const float* __restrict__ Wg,
    const float* __restrict__ usq, const float* __restrict__ vsq,
    double* __restrict__ acc)
{
    __shared__ alignas(16) char smem[BM * BK * 2 + BN * BK * 2];  // 32 KiB
    __shared__ float red1[4], red2[4];
    char* As = smem;
    char* Bs = smem + BM * BK * 2;
    float* recs = (float*)smem;   // epilogue: 64 x 128 f32 (col-swizzled)

    const int t    = threadIdx.x;
    const int lane = t & 63;
    const int wave = t >> 6;
    const int wm   = wave >> 1;
    const int wn   = wave & 1;

    const int bid    = blockIdx.x;          // row-major (R1 map: L3 retention)
    const int tile_m = bid >> 6;
    const int tile_n = bid & 63;
    const int row0   = tile_m * BM;
    const int col0   = tile_n * BN;

    const f32x4 zero = {0.f, 0.f, 0.f, 0.f};
    f32x4 a[4][4];
    #pragma unroll
    for (int i = 0; i < 4; ++i)
        #pragma unroll
        for (int j = 0; j < 4; ++j) a[i][j] = zero;

    auto As3 = (__attribute__((address_space(3))) char*)As;
    auto Bs3 = (__attribute__((address_space(3))) char*)Bs;

    for (int kt = 0; kt < D_DIM / BK; ++kt) {
        const int k0 = kt * BK;
        #pragma unroll
        for (int c = 0; c < 4; ++c) {
            int s   = c * 256 + t;
            int row = s >> 3;
            int kg  = s & 7;
            int kgs = kg ^ (row & 7);    // inverse-swizzled global source
            __builtin_amdgcn_global_load_lds(
                (const __attribute__((address_space(1))) void*)(Ub + (size_t)(row0 + row) * D_DIM + k0 + kgs * 8),
                (__attribute__((address_space(3))) void*)(As3 + s * 16), 16, 0, 0);
            __builtin_amdgcn_global_load_lds(
                (const __attribute__((address_space(1))) void*)(Vb + (size_t)(col0 + row) * D_DIM + k0 + kgs * 8),
                (__attribute__((address_space(3))) void*)(Bs3 + s * 16), 16, 0, 0);
        }
        __syncthreads();   // drains vmcnt: required for global_load_lds visibility

        #pragma unroll
        for (int kc = 0; kc < 2; ++kc) {
            bf16x8 af[4], bfr[4];
            const int kgw = kc * 4 + (lane >> 4);
            #pragma unroll
            for (int i = 0; i < 4; ++i) {
                int ra = wm * 64 + i * 16 + (lane & 15);
                af[i]  = *reinterpret_cast<const bf16x8*>(As + ra * (BK * 2) + ((kgw ^ (ra & 7)) * 16));
                int rb = wn * 64 + i * 16 + (lane & 15);
                bfr[i] = *reinterpret_cast<const bf16x8*>(Bs + rb * (BK * 2) + ((kgw ^ (rb & 7)) * 16));
            }
            #pragma unroll
            for (int i = 0; i < 4; ++i)
                #pragma unroll
                for (int j = 0; j < 4; ++j)
                    a[i][j] = __builtin_amdgcn_mfma_f32_16x16x32_bf16(af[i], bfr[j], a[i][j], 0, 0, 0);
        }
        __syncthreads();
    }

    // ---- epilogue ----
    const int rloc = t >> 5;         // 0..7
    const int cg   = t & 31;         // column group (4 floats)
    const int c4   = cg * 4;         // 0..124
    const f32x4 vs = *reinterpret_cast<const f32x4*>(vsq + col0 + c4);

    float s1 = 0.f, s2 = 0.f;

    // three named M/W register sets (all compile-time indexed)
    f32x4 mA[4], wA[4]; float uA[4];
    f32x4 mB[4], wB[4]; float uB[4];
    f32x4 mC[4], wC[4]; float uC[4];

    #define ISSUE(S, h, kk)                                                          \
        do {                                                                         \
            _Pragma("unroll")                                                        \
            for (int b = 0; b < 4; ++b) {                                            \
                int r    = rloc + ((kk) * 4 + b) * 8;                                \
                int grow = row0 + (h) * 64 + r;                                      \
                m##S[b] = *reinterpret_cast<const f32x4*>(Mg + (size_t)grow * N_DIM + col0 + c4); \
                w##S[b] = *reinterpret_cast<const f32x4*>(Wg + (size_t)grow * N_DIM + col0 + c4); \
                u##S[b] = usq[grow];                                                 \
            }                                                                        \
        } while (0)

    #define CONSUME(S, kk)                                                           \
        do {                                                                         \
            _Pragma("unroll")                                                        \
            for (int b = 0; b < 4; ++b) {                                            \
                int r = rloc + ((kk) * 4 + b) * 8;                                   \
                f32x4 rc = *reinterpret_cast<const f32x4*>(                          \
                    &recs[r * 128 + ((cg ^ (r & 7)) << 2)]);                         \
                _Pragma("unroll")                                                    \
                for (int c = 0; c < 4; ++c) {                                        \
                    float d = rc[c] - m##S[b][c];                                    \
                    s1 = fmaf(d, d, s1);                                             \
                    s2 = fmaf(w##S[b][c], u##S[b] + vs[c] - 2.f * rc[c], s2);        \
                }                                                                    \
            }                                                                        \
        } while (0)

    // C/D layout (16x16x32): col = lane&15, row = (lane>>4)*4 + reg
    #define DUMP_HALF(h)                                                             \
        do {                                                                         \
            if (wm == (h)) {                                                         \
                _Pragma("unroll")                                                    \
                for (int i = 0; i < 4; ++i)                                          \
                    _Pragma("unroll")                                                \
                    for (int j = 0; j < 4; ++j)                                      \
                        _Pragma("unroll")                                            \
                        for (int q = 0; q < 4; ++q) {                                \
                            int r = i * 16 + (lane >> 4) * 4 + q;                    \
                            int c = wn * 64 + j * 16 + (lane & 15);                  \
                            recs[r * 128 + ((((c >> 2) ^ (r & 7))) << 2) + (c & 3)]  \
                                = a[i][j][q];                                        \
                        }                                                            \
            }                                                                        \
        } while (0)

    #define LGKM0_BAR() do { \
        asm volatile("s_waitcnt lgkmcnt(0)" ::: "memory"); \
        __builtin_amdgcn_s_barrier(); } while (0)

    // loads for h0 (both batches) and h1/batch0 issued up front -> in flight
    // through dump + barrier; vmcnt is never drained below.
    ISSUE(A, 0, 0);
    ISSUE(B, 0, 1);
    ISSUE(C, 1, 0);

    DUMP_HALF(0);
    LGKM0_BAR();

    CONSUME(A, 0);
    ISSUE(A, 1, 1);          // reuse set A for h1/batch1 (WAR ordered by reads)
    CONSUME(B, 1);
    LGKM0_BAR();             // all half-0 recs reads complete

    DUMP_HALF(1);
    LGKM0_BAR();

    CONSUME(C, 0);
    CONSUME(A, 1);

    #undef ISSUE
    #undef CONSUME
    #undef DUMP_HALF
    #undef LGKM0_BAR

    // ---- block reduction + atomics ----
    #pragma unroll
    for (int o = 32; o > 0; o >>= 1) {
        s1 += __shfl_down(s1, o, 64);
        s2 += __shfl_down(s2, o, 64);
    }
    if (lane == 0) { red1[wave] = s1; red2[wave] = s2; }
    __syncthreads();
    if (t == 0) {
        double a1s = (double)red1[0] + red1[1] + red1[2] + red1[3];
        double a2s = (double)red2[0] + red2[1] + red2[2] + red2[3];
        atomicAdd(acc, a1s);
        atomicAdd(acc + 1, a2s);
    }
}

// ---------------- finalize ----------------
__global__ void finalize_kernel(const double* __restrict__ acc,
                                const float* __restrict__ alpha,
                                float* __restrict__ out)
{
    double tot = acc[0] + (double)alpha[0] * acc[1];
    out[0] = (float)(tot / ((double)N_DIM * (double)N_DIM));
}

extern "C" void kernel_launch(void* const* d_in, const int* in_sizes, int n_in,
                              void* d_out, int out_size, void* d_ws, size_t ws_size,
                              hipStream_t stream) {
    const float* U     = (const float*)d_in[0];
    const float* V     = (const float*)d_in[1];
    const float* Mg    = (const float*)d_in[2];
    const float* Wg    = (const float*)d_in[3];
    const float* alpha = (const float*)d_in[4];

    char* ws = (char*)d_ws;
    unsigned short* Ub = (unsigned short*)ws;                          // 8 MiB
    unsigned short* Vb = (unsigned short*)(ws + 8u * 1024 * 1024);     // 8 MiB
    float* usq = (float*)(ws + 16u * 1024 * 1024);                     // 32 KiB
    float* vsq = (float*)(ws + 16u * 1024 * 1024 + 32u * 1024);       // 32 KiB
    double* acc = (double*)(ws + 16u * 1024 * 1024 + 64u * 1024);     // 16 B

    hipMemsetAsync(acc, 0, 2 * sizeof(double), stream);
    prep_kernel<<<2 * N_DIM, 256, 0, stream>>>(U, V, Ub, Vb, usq, vsq);
    fused_kernel<<<(N_DIM / BM) * (N_DIM / BN), 256, 0, stream>>>(
        Ub, Vb, Mg, Wg, usq, vsq, acc);
    finalize_kernel<<<1, 1, 0, stream>>>(acc, alpha, (float*)d_out);
}